// Round 9
// baseline (574.207 us; speedup 1.0000x reference)
//
#include <hip/hip_runtime.h>

#define NB 16
#define NC 256
#define NT 2048
#define NK 1024
#define NQ (NB * NT)     // 32768 queries
#define TQB 128          // queries (t) per block
#define HALF_B 16384     // bytes of one (hi or lo) chunk: 32*256*2
#define CHUNK_B 32768    // hi+lo chunk bytes
#define AMB_TH 0.05f     // final top-2 gap threshold (>> bf16x3 error ~0.005)

typedef __attribute__((ext_vector_type(8))) short short8v;
typedef __attribute__((ext_vector_type(16))) float f32x16;

__device__ __forceinline__ unsigned bf16_rne(float x) {
  unsigned u = __float_as_uint(x);
  return (u + 0x7FFFu + ((u >> 16) & 1u)) >> 16;
}

// Prep: split codebook into bf16 hi/lo, pre-swizzled per 32-code chunk so linear
// global_load_lds staging lands in the XOR-swizzled LDS layout. cnorm = 0.5*||c||^2.
// Also zeroes the cleanup worklist counter (d_ws is re-poisoned before every launch).
__global__ __launch_bounds__(256) void vq_prep(const float* __restrict__ cb,
                                               char* __restrict__ cbs,
                                               float* __restrict__ cnorm,
                                               int* __restrict__ cnt) {
  if (blockIdx.x == 0 && threadIdx.x == 0) *cnt = 0;
  const int k = blockIdx.x, c = threadIdx.x;
  float v = cb[k * NC + c];
  unsigned hb = bf16_rne(v);
  float hf = __uint_as_float(hb << 16);
  unsigned lb = bf16_rne(v - hf);
  const int chunk = k >> 5, r = k & 31;
  // element (r,c) at byte r*512 + ((c>>3 ^ r)&31)*16 + (c&7)*2  (16B-slot XOR swizzle)
  const int off = (r << 9) + (((((c >> 3)) ^ r) & 31) << 4) + ((c & 7) << 1);
  *(unsigned short*)(cbs + (size_t)chunk * CHUNK_B + off) = (unsigned short)hb;
  *(unsigned short*)(cbs + (size_t)chunk * CHUNK_B + HALF_B + off) = (unsigned short)lb;
  float s = v * v;
  #pragma unroll
  for (int o = 32; o > 0; o >>= 1) s += __shfl_down(s, o, 64);
  __shared__ float wsum[4];
  if ((threadIdx.x & 63) == 0) wsum[threadIdx.x >> 6] = s;
  __syncthreads();
  if (threadIdx.x == 0) cnorm[k] = 0.5f * (wsum[0] + wsum[1] + wsum[2] + wsum[3]);
}

// Main: grid 512 = 256 query-tiles x 2 codebook halves (K-split for occupancy:
// 2048 waves -> 2 waves/SIMD). Per block: 128 queries, 16 chunks of 32 codes.
// Writes per-query top-2 partials (best, second, idx) for its half.
__global__ __launch_bounds__(256, 2) void vq_main(const float* __restrict__ z,
                                                  const char* __restrict__ cbs,
                                                  const float* __restrict__ cnorm,
                                                  float* __restrict__ pb,
                                                  float* __restrict__ ps,
                                                  int* __restrict__ pi) {
  __shared__ char ldsb[2 * CHUNK_B];   // 64 KB double buffer -> 2 blocks/CU
  const int tid = threadIdx.x;
  const int w = tid >> 6, l = tid & 63;
  const int r = l & 31;      // A row / B col / C col within 32x32 tile
  const int h = l >> 5;      // k-group half
  const int kh = blockIdx.x >> 8;          // codebook half (chunks kh*16 .. +16)
  const int qt = blockIdx.x & 255;
  const int b = qt >> 4;
  const int t0 = (qt & 15) * TQB;
  const int tq = t0 + (w << 5) + r;        // this lane's query t

  // ---- load A (z) and split to bf16 hi/lo fragments: k=8h+e -> channel 16s+8h+e ----
  short8v Ahi[16], Alo[16];
  #pragma unroll
  for (int s = 0; s < 16; ++s) {
    const float* zp = z + ((size_t)(b * NC + (s << 4) + (h << 3))) * NT + tq;
    #pragma unroll
    for (int e = 0; e < 8; ++e) {
      float v = zp[(size_t)e * NT];
      unsigned hb = bf16_rne(v);
      float hf = __uint_as_float(hb << 16);
      unsigned lb = bf16_rne(v - hf);
      Ahi[s][e] = (short)hb;
      Alo[s][e] = (short)lb;
    }
  }

  float bestv[16], secv[16];
  int besti[16];
  #pragma unroll
  for (int i = 0; i < 16; ++i) {
    bestv[i] = -3.402823466e38f; secv[i] = -3.402823466e38f; besti[i] = 0;
  }

#define STAGE(CH, BSEL) do {                                                      \
    const char* _s = cbs + (size_t)(CH) * CHUNK_B + ((size_t)tid << 4);           \
    char* _d = ldsb + (BSEL) * CHUNK_B + (w << 10);                               \
    _Pragma("unroll")                                                             \
    for (int _j = 0; _j < 8; ++_j)                                                \
      __builtin_amdgcn_global_load_lds(                                           \
          (const __attribute__((address_space(1))) void*)(_s + (_j << 12)),       \
          (__attribute__((address_space(3))) void*)(_d + (_j << 12)), 16, 0, 0);  \
  } while (0)

  const int ch0 = kh << 4;
  STAGE(ch0, 0);
  int bufsel = 0;
  for (int cc = 0; cc < 16; ++cc) {
    const int ch = ch0 + cc;
    STAGE(ch0 + ((cc + 1) & 15), bufsel ^ 1);           // prefetch next (wrap: dead, harmless)
    asm volatile("s_waitcnt vmcnt(8)" ::: "memory");     // current chunk landed (this wave)
    __builtin_amdgcn_s_barrier();                        // ...and all other waves' quarters
    float cn = cnorm[(ch << 5) + r];
    f32x16 accA = {}, accBC = {};   // hi*hi chain; folded (hi*lo + lo*hi) chain
    const char* Lh = ldsb + bufsel * CHUNK_B;
    #pragma unroll
    for (int s = 0; s < 16; ++s) {
      const int off = (r << 9) + (((((s << 1) + h) ^ r) & 31) << 4);
      short8v Bh = *(const short8v*)(Lh + off);
      short8v Bl = *(const short8v*)(Lh + HALF_B + off);
      accA  = __builtin_amdgcn_mfma_f32_32x32x16_bf16(Ahi[s], Bh, accA, 0, 0, 0);
      accBC = __builtin_amdgcn_mfma_f32_32x32x16_bf16(Alo[s], Bh, accBC, 0, 0, 0);
      accBC = __builtin_amdgcn_mfma_f32_32x32x16_bf16(Ahi[s], Bl, accBC, 0, 0, 0);
    }
    __builtin_amdgcn_s_barrier();                        // done reading this buffer
    const int kidx = (ch << 5) + r;                      // C/D col = lane&31 (m101)
    #pragma unroll
    for (int i = 0; i < 16; ++i) {
      float sc = (accA[i] + accBC[i]) - cn;
      if (sc > bestv[i]) { secv[i] = bestv[i]; bestv[i] = sc; besti[i] = kidx; }
      else               { secv[i] = fmaxf(secv[i], sc); }
    }
    bufsel ^= 1;
  }
#undef STAGE

  // ---- top-2 merge over the 32 code-columns (lane bits 0..4; stays in h-half) ----
  #pragma unroll
  for (int st = 1; st < 32; st <<= 1) {
    #pragma unroll
    for (int i = 0; i < 16; ++i) {
      float ob = __shfl_xor(bestv[i], st, 64);
      float os = __shfl_xor(secv[i], st, 64);
      int   oi = __shfl_xor(besti[i], st, 64);
      if (ob > bestv[i]) {
        secv[i] = fmaxf(bestv[i], os);     // second of union
        bestv[i] = ob; besti[i] = oi;
      } else {
        secv[i] = fmaxf(secv[i], ob);
        if (ob == bestv[i] && oi < besti[i]) besti[i] = oi;  // first-index tie-break
      }
    }
  }
  if (r == 0) {
    #pragma unroll
    for (int i = 0; i < 16; ++i) {
      const int row = (i & 3) + ((i >> 2) << 3) + (h << 2);   // m101 C/D row map
      const int qg = b * NT + t0 + (w << 5) + row;
      const int o = kh * NQ + qg;
      pb[o] = bestv[i]; ps[o] = secv[i]; pi[o] = besti[i];
    }
  }
  asm volatile("s_waitcnt vmcnt(0)" ::: "memory");       // drain dead wrap-prefetch
}

// Merge: combine the two K-half partials, write indices, gather z_q, build worklist.
__global__ __launch_bounds__(256) void vq_merge(const float* __restrict__ cb,
                                                const float* __restrict__ pb,
                                                const float* __restrict__ ps,
                                                const int* __restrict__ pi,
                                                float* __restrict__ out,
                                                int* __restrict__ wl,
                                                int* __restrict__ cnt) {
  __shared__ int idx_sh[TQB];
  const int tid = threadIdx.x;
  const int b = blockIdx.x >> 4;
  const int t0 = (blockIdx.x & 15) * TQB;
  if (tid < TQB) {
    const int qg = b * NT + t0 + tid;
    float b0 = pb[qg], s0 = ps[qg];           int i0 = pi[qg];
    float b1 = pb[NQ + qg], s1 = ps[NQ + qg]; int i1 = pi[NQ + qg];
    float bb, ss; int ii;
    if (b0 >= b1) { bb = b0; ii = i0; ss = fmaxf(s0, b1); }  // tie -> lower half's idx
    else          { bb = b1; ii = i1; ss = fmaxf(s1, b0); }
    idx_sh[tid] = ii;
    out[(size_t)NB * NC * NT + qg] = (float)ii;
    if (bb - ss <= AMB_TH) { int p = atomicAdd(cnt, 1); wl[p] = qg; }
  }
  __syncthreads();
  // gather: z_q[b][c][t] = cb[idx[t]][c], t-contiguous coalesced stores
  const int tt = tid & 127;
  const int chi = tid >> 7;
  const int myidx = idx_sh[tt];
  const float* crow = cb + (size_t)myidx * NC;
  const size_t obase = (size_t)b * NC * NT + (size_t)t0 + tt;
  #pragma unroll 8
  for (int c0 = 0; c0 < NC; c0 += 2) {
    const int c = c0 + chi;
    out[obase + (size_t)c * NT] = crow[c];
  }
}

// Cleanup: exact fp32 rescan over the compacted worklist (fixed 512 blocks).
__global__ __launch_bounds__(256) void vq_cleanup(const float* __restrict__ z,
                                                  const float* __restrict__ cb,
                                                  const int* __restrict__ wl,
                                                  const int* __restrict__ cnt,
                                                  float* __restrict__ out) {
  __shared__ float zsh[NC];
  __shared__ unsigned long long red[5];
  const int tid = threadIdx.x;
  const int n = *cnt;                        // uniform across all threads
  for (int i = blockIdx.x; i < n; i += 512) {
    const int q = wl[i];
    const int b = q >> 11, t = q & (NT - 1);
    zsh[tid] = z[((size_t)b * NC + tid) * NT + t];
    __syncthreads();
    float bd = 3.402823466e38f; int bi = NK;
    #pragma unroll
    for (int j = 0; j < 4; ++j) {
      const int k = (j << 8) + tid;          // ascending k per thread
      const float* ck = cb + (size_t)k * NC;
      float d0 = 0.f, d1 = 0.f, d2 = 0.f, d3 = 0.f;
      for (int c = 0; c < NC; c += 4) {
        float4 zz = *(const float4*)&zsh[c];
        float4 cc = *(const float4*)&ck[c];
        float e0 = zz.x - cc.x, e1 = zz.y - cc.y, e2 = zz.z - cc.z, e3 = zz.w - cc.w;
        d0 = fmaf(e0, e0, d0); d1 = fmaf(e1, e1, d1);
        d2 = fmaf(e2, e2, d2); d3 = fmaf(e3, e3, d3);
      }
      float d = (d0 + d1) + (d2 + d3);
      if (d < bd) { bd = d; bi = k; }
    }
    unsigned long long p = ((unsigned long long)__float_as_uint(bd) << 32) | (unsigned)bi;
    #pragma unroll
    for (int st = 1; st < 64; st <<= 1) {
      unsigned long long o = __shfl_xor(p, st, 64);
      if (o < p) p = o;
    }
    if ((tid & 63) == 0) red[tid >> 6] = p;
    __syncthreads();
    if (tid == 0) {
      unsigned long long m = red[0];
      for (int ww = 1; ww < 4; ++ww) if (red[ww] < m) m = red[ww];
      red[4] = m;
    }
    __syncthreads();
    const int best = (int)(red[4] & 0xFFFFFFFFull);
    if (tid == 0) out[(size_t)NB * NC * NT + q] = (float)best;
    out[((size_t)b * NC + tid) * NT + t] = cb[(size_t)best * NC + tid];
    __syncthreads();                         // zsh/red reuse next iteration
  }
}

extern "C" void kernel_launch(void* const* d_in, const int* in_sizes, int n_in,
                              void* d_out, int out_size, void* d_ws, size_t ws_size,
                              hipStream_t stream) {
  const float* z = (const float*)d_in[0];
  const float* cb = (const float*)d_in[1];
  float* out = (float*)d_out;
  char* base = (char*)d_ws;
  char* cbs    = base;                                   // 1 MB swizzled hi/lo
  float* cnorm = (float*)(base + (1 << 20));             // 4 KB
  int* cnt     = (int*)(base + (1 << 20) + 4096);        // 4 B (padded)
  int* wl      = (int*)(base + (1 << 20) + 8192);        // 128 KB worklist
  float* pb    = (float*)(base + (1 << 20) + 8192 + (128 << 10));  // 2*NQ floats
  float* ps    = pb + 2 * NQ;                            // 2*NQ floats
  int*   pi    = (int*)(ps + 2 * NQ);                    // 2*NQ ints   (total ~1.9 MB)

  vq_prep<<<NK, NC, 0, stream>>>(cb, cbs, cnorm, cnt);
  vq_main<<<512, 256, 0, stream>>>(z, cbs, cnorm, pb, ps, pi);
  vq_merge<<<256, 256, 0, stream>>>(cb, pb, ps, pi, out, wl, cnt);
  vq_cleanup<<<512, 256, 0, stream>>>(z, cb, wl, cnt, out);
}